// Round 1
// 740.454 us; speedup vs baseline: 1.0147x; 1.0147x over previous
//
#include <hip/hip_runtime.h>

#define NN 4096
#define BB 4
#define FF 64

typedef __attribute__((ext_vector_type(8))) short short8;
typedef __attribute__((ext_vector_type(4))) float f32x4;

__device__ inline unsigned short f2bf(float f) {
    unsigned int u = __float_as_uint(f);
    u += 0x7fffu + ((u >> 16) & 1u);   // RNE; inputs finite
    return (unsigned short)(u >> 16);
}

__device__ inline short8 cvt8(float4 lo, float4 hi) {
    short8 r;
    r[0] = (short)f2bf(lo.x); r[1] = (short)f2bf(lo.y);
    r[2] = (short)f2bf(lo.z); r[3] = (short)f2bf(lo.w);
    r[4] = (short)f2bf(hi.x); r[5] = (short)f2bf(hi.y);
    r[6] = (short)f2bf(hi.z); r[7] = (short)f2bf(hi.w);
    return r;
}

// Kernel 1: Zt[i][b][f][k] = (X[b] @ w_i)[k][f] in bf16 (f-major).
// fp32 accumulation (numerics match previous version). X staged once in LDS,
// read via wave-uniform ds_read_b128 broadcasts hoisted out of the i-loop.
// Stores go straight to global (each thread's 8 k-values are contiguous in the
// f-major layout) -- no LDS transpose, no store barriers.
__global__ __launch_bounds__(512) void prep_z(
    const float* __restrict__ X,
    const float* __restrict__ w0, const float* __restrict__ w1, const float* __restrict__ w2,
    unsigned short* __restrict__ Zt)
{
    __shared__ float Xs[64][68];
    const int blk = blockIdx.x;          // b*64 + ktile
    const int b = blk >> 6;
    const int k0 = (blk & 63) << 6;
    const int t = threadIdx.x;
    {
        const int kk = t >> 3, c8 = (t & 7) * 8;
        const float* src = X + ((size_t)(b * NN + k0 + kk)) * FF + c8;
        *(float4*)&Xs[kk][c8]     = *(const float4*)(src);
        *(float4*)&Xs[kk][c8 + 4] = *(const float4*)(src + 4);
    }
    __syncthreads();
    const int lane = t & 63;             // f index
    const int w = t >> 6;                // 8 waves; wave handles rows k0+w*8 .. +7
    float acc0[8] = {}, acc1[8] = {}, acc2[8] = {};
    #pragma unroll 2
    for (int c4 = 0; c4 < 16; ++c4) {
        float4 xv[8];
        #pragma unroll
        for (int j = 0; j < 8; ++j) xv[j] = *(const float4*)&Xs[w * 8 + j][c4 * 4];
        #pragma unroll
        for (int cc = 0; cc < 4; ++cc) {
            const int c = c4 * 4 + cc;
            const float wv0 = w0[c * FF + lane];
            const float wv1 = w1[c * FF + lane];
            const float wv2 = w2[c * FF + lane];
            #pragma unroll
            for (int j = 0; j < 8; ++j) {
                const float x = ((const float*)&xv[j])[cc];
                acc0[j] = fmaf(x, wv0, acc0[j]);
                acc1[j] = fmaf(x, wv1, acc1[j]);
                acc2[j] = fmaf(x, wv2, acc2[j]);
            }
        }
    }
    unsigned short* zp = Zt + ((size_t)(b * FF + lane)) * NN + k0 + w * 8;
    const size_t plane = (size_t)BB * FF * NN;
    {
        short8 v;
        #pragma unroll
        for (int e = 0; e < 8; ++e) v[e] = (short)f2bf(acc0[e]);
        *(short8*)zp = v;
    }
    zp += plane;
    {
        short8 v;
        #pragma unroll
        for (int e = 0; e < 8; ++e) v[e] = (short)f2bf(acc1[e]);
        *(short8*)zp = v;
    }
    zp += plane;
    {
        short8 v;
        #pragma unroll
        for (int e = 0; e < 8; ++e) v[e] = (short)f2bf(acc2[e]);
        *(short8*)zp = v;
    }
}

#define MFMA8(AF0, AF1, Z0, Z1, Z2, Z3)                                                   \
    acc[0][0] = __builtin_amdgcn_mfma_f32_16x16x32_bf16(AF0, Z0, acc[0][0], 0, 0, 0);     \
    acc[0][1] = __builtin_amdgcn_mfma_f32_16x16x32_bf16(AF0, Z1, acc[0][1], 0, 0, 0);     \
    acc[0][2] = __builtin_amdgcn_mfma_f32_16x16x32_bf16(AF0, Z2, acc[0][2], 0, 0, 0);     \
    acc[0][3] = __builtin_amdgcn_mfma_f32_16x16x32_bf16(AF0, Z3, acc[0][3], 0, 0, 0);     \
    acc[1][0] = __builtin_amdgcn_mfma_f32_16x16x32_bf16(AF1, Z0, acc[1][0], 0, 0, 0);     \
    acc[1][1] = __builtin_amdgcn_mfma_f32_16x16x32_bf16(AF1, Z1, acc[1][1], 0, 0, 0);     \
    acc[1][2] = __builtin_amdgcn_mfma_f32_16x16x32_bf16(AF1, Z2, acc[1][2], 0, 0, 0);     \
    acc[1][3] = __builtin_amdgcn_mfma_f32_16x16x32_bf16(AF1, Z3, acc[1][3], 0, 0, 0);

// Kernel 2: out[b][m][f] = relu( sum_i A_i[b] @ Z_i[b] ).
// Barrier-free streaming: MFMA fragments loaded DIRECTLY from global (A as fp32,
// converted in-register; Zt bf16 f-major gives contiguous 16B B-fragments).
// Grid 512 blocks x 384 threads (6 waves): wave = ig*2+kh owns A_ig, 32 output
// rows, k-half [kh*2048, +2048). Unroll-2 register double-buffer, no LDS, no
// __syncthreads in the 64-iteration main loop. 2 blocks/CU = 12 independent
// wave-streams/CU. XCD-chunked swizzle keeps one b (1.5 MB of Zt) per XCD L2.
// Epilogue: 3-phase LDS reduction of the 6 partials + relu + coalesced store.
__global__ __launch_bounds__(384, 3) void gnn_main(
    const float* __restrict__ A0, const float* __restrict__ A1, const float* __restrict__ A2,
    const unsigned short* __restrict__ Zt,
    float* __restrict__ out)
{
    __shared__ float red[2][32][68];
    const int nb = (int)blockIdx.x;
    const int swz = (nb & 7) * 64 + (nb >> 3);   // bijective: 512 % 8 == 0
    const int b  = swz >> 7;
    const int m0 = (swz & 127) << 5;
    const int t = threadIdx.x;
    const int lane = t & 63;
    const int wave = t >> 6;      // 0..5
    const int ig = wave >> 1;     // which A matrix
    const int kh = wave & 1;      // which k half
    const int r = lane & 15;      // fragment row / col
    const int g = lane >> 4;      // k sub-group

    const float* Ai = (ig == 0) ? A0 : (ig == 1) ? A1 : A2;
    const float* pA0 = Ai + ((size_t)(b * NN + m0 + r)) * NN + kh * 2048 + g * 8;
    const float* pA1 = pA0 + (size_t)16 * NN;
    const unsigned short* pZ0 =
        Zt + ((size_t)((ig * BB + b) * FF + r)) * NN + kh * 2048 + g * 8;
    const unsigned short* pZ1 = pZ0 + (size_t)16 * NN;
    const unsigned short* pZ2 = pZ0 + (size_t)32 * NN;
    const unsigned short* pZ3 = pZ0 + (size_t)48 * NN;

    f32x4 acc[2][4] = {};

    // preload iterations 0 (a*/z0*) and 1 (b*/z1*); k advances 32 per iter
    float4 a00 = *(const float4*)(pA0);      float4 a01 = *(const float4*)(pA0 + 4);
    float4 a10 = *(const float4*)(pA1);      float4 a11 = *(const float4*)(pA1 + 4);
    short8 z00 = *(const short8*)(pZ0);      short8 z01 = *(const short8*)(pZ1);
    short8 z02 = *(const short8*)(pZ2);      short8 z03 = *(const short8*)(pZ3);
    float4 b00 = *(const float4*)(pA0 + 32); float4 b01 = *(const float4*)(pA0 + 36);
    float4 b10 = *(const float4*)(pA1 + 32); float4 b11 = *(const float4*)(pA1 + 36);
    short8 z10 = *(const short8*)(pZ0 + 32); short8 z11 = *(const short8*)(pZ1 + 32);
    short8 z12 = *(const short8*)(pZ2 + 32); short8 z13 = *(const short8*)(pZ3 + 32);
    pA0 += 64; pA1 += 64; pZ0 += 64; pZ1 += 64; pZ2 += 64; pZ3 += 64;

    for (int it = 0; it < 62; it += 2) {
        // even half: consume buf0, prefetch iter it+2 (A right after cvt frees
        // the regs; Z after the MFMAs that consume z0*)
        short8 af0 = cvt8(a00, a01);
        short8 af1 = cvt8(a10, a11);
        a00 = *(const float4*)(pA0);      a01 = *(const float4*)(pA0 + 4);
        a10 = *(const float4*)(pA1);      a11 = *(const float4*)(pA1 + 4);
        MFMA8(af0, af1, z00, z01, z02, z03)
        z00 = *(const short8*)(pZ0);      z01 = *(const short8*)(pZ1);
        z02 = *(const short8*)(pZ2);      z03 = *(const short8*)(pZ3);

        // odd half: consume buf1, prefetch iter it+3
        af0 = cvt8(b00, b01);
        af1 = cvt8(b10, b11);
        b00 = *(const float4*)(pA0 + 32); b01 = *(const float4*)(pA0 + 36);
        b10 = *(const float4*)(pA1 + 32); b11 = *(const float4*)(pA1 + 36);
        MFMA8(af0, af1, z10, z11, z12, z13)
        z10 = *(const short8*)(pZ0 + 32); z11 = *(const short8*)(pZ1 + 32);
        z12 = *(const short8*)(pZ2 + 32); z13 = *(const short8*)(pZ3 + 32);

        pA0 += 64; pA1 += 64; pZ0 += 64; pZ1 += 64; pZ2 += 64; pZ3 += 64;
    }
    {   // tail: iterations 62, 63 (already loaded)
        short8 af0 = cvt8(a00, a01);
        short8 af1 = cvt8(a10, a11);
        MFMA8(af0, af1, z00, z01, z02, z03)
        af0 = cvt8(b00, b01);
        af1 = cvt8(b10, b11);
        MFMA8(af0, af1, z10, z11, z12, z13)
    }

    // epilogue: reduce 6 partials (3 ig x 2 kh buffers), relu, store.
    // C/D layout: col = lane&15, row = (lane>>4)*4 + j  (verified mapping).
    float* buf = &red[kh][0][0];
    #pragma unroll
    for (int gph = 0; gph < 3; ++gph) {
        if (ig == gph) {
            #pragma unroll
            for (int mf = 0; mf < 2; ++mf)
                #pragma unroll
                for (int nt = 0; nt < 4; ++nt)
                    #pragma unroll
                    for (int j = 0; j < 4; ++j) {
                        const int row = mf * 16 + g * 4 + j;
                        const int col = nt * 16 + r;
                        if (gph == 0) buf[row * 68 + col]  = acc[mf][nt][j];
                        else          buf[row * 68 + col] += acc[mf][nt][j];
                    }
        }
        __syncthreads();
    }
    for (int ch = t; ch < 512; ch += 384) {   // 32x64 f32 = 512 float4 chunks
        const int row = ch >> 4, c0 = (ch & 15) << 2;
        const float4 v0 = *(const float4*)&red[0][row][c0];
        const float4 v1 = *(const float4*)&red[1][row][c0];
        float4 v;
        v.x = fmaxf(v0.x + v1.x, 0.f);
        v.y = fmaxf(v0.y + v1.y, 0.f);
        v.z = fmaxf(v0.z + v1.z, 0.f);
        v.w = fmaxf(v0.w + v1.w, 0.f);
        *(float4*)(out + ((size_t)(b * NN + m0 + row)) * FF + c0) = v;
    }
}

extern "C" void kernel_launch(void* const* d_in, const int* in_sizes, int n_in,
                              void* d_out, int out_size, void* d_ws, size_t ws_size,
                              hipStream_t stream) {
    const float* X  = (const float*)d_in[0];
    const float* A0 = (const float*)d_in[1];
    const float* A1 = (const float*)d_in[2];
    const float* A2 = (const float*)d_in[3];
    const float* w0 = (const float*)d_in[4];
    const float* w1 = (const float*)d_in[5];
    const float* w2 = (const float*)d_in[6];
    float* out = (float*)d_out;
    unsigned short* Zt = (unsigned short*)d_ws;  // 3*4*64*4096 bf16 = 6.3 MB

    prep_z<<<256, 512, 0, stream>>>(X, w0, w1, w2, Zt);
    gnn_main<<<512, 384, 0, stream>>>(A0, A1, A2, Zt, out);
}